// Round 1
// baseline (676.365 us; speedup 1.0000x reference)
//
#include <hip/hip_runtime.h>
#include <hip/hip_bf16.h>
#include <cmath>

#define N_TOK 1024
#define DIM   1024
#define FFN   2048
#define NE    32
#define TOPK  4
#define TM    192
#define TN    64
#define BK    32
#define BS_STRIDE 40   // bf16 elems per Bs row (80 B): 2-way bank aliasing only

typedef __attribute__((ext_vector_type(8))) short bf16x8;
typedef __attribute__((ext_vector_type(4))) float f32x4;

#define GLOBAL_AS __attribute__((address_space(1)))
#define LDS_AS    __attribute__((address_space(3)))

__device__ __forceinline__ void g2lds16(const void* g, void* l) {
    __builtin_amdgcn_global_load_lds((const GLOBAL_AS void*)g, (LDS_AS void*)l, 16, 0, 0);
}

// ---------------- zero out buffer (for atomic combine) ----------------
__global__ void zero_kernel(float4* __restrict__ p) {
    p[blockIdx.x * 256 + threadIdx.x] = float4{0.f, 0.f, 0.f, 0.f};
}

// ---------------- router (+ x->bf16): logits, probs, top-4 ----------------
__global__ __launch_bounds__(256) void router_kernel(
        const float* __restrict__ x, const float* __restrict__ gw,
        const float* __restrict__ gb, float* __restrict__ probs_mat,
        int* __restrict__ top_idx, float* __restrict__ top_w,
        __hip_bfloat16* __restrict__ xb) {
    __shared__ float part[8][32];
    int t = threadIdx.x;
    int token = blockIdx.x;
    const float* xr = x + (size_t)token * DIM;
    // fused convert x -> bf16
    {
        float4 v = *(const float4*)&xr[t * 4];
        union { __hip_bfloat16 h[4]; ushort4 u; } pk;
        pk.h[0] = __float2bfloat16(v.x); pk.h[1] = __float2bfloat16(v.y);
        pk.h[2] = __float2bfloat16(v.z); pk.h[3] = __float2bfloat16(v.w);
        *(ushort4*)&xb[(size_t)token * DIM + t * 4] = pk.u;
    }
    int e = t & 31, p = t >> 5;
    float acc = 0.f;
    int i0 = p * (DIM / 8);
    for (int i = 0; i < DIM / 8; ++i)
        acc += xr[i0 + i] * gw[(size_t)(i0 + i) * NE + e];
    part[p][e] = acc;
    __syncthreads();
    if (t < 64) {
        float l = -3e38f;
        if (t < 32) {
            l = gb[t];
            for (int q = 0; q < 8; ++q) l += part[q][t];
        }
        // full-softmax probs (for aux)
        float m = l;
        for (int off = 32; off >= 1; off >>= 1) m = fmaxf(m, __shfl_xor(m, off, 64));
        float ex = (t < 32) ? expf(l - m) : 0.f;
        float den = ex;
        for (int off = 32; off >= 1; off >>= 1) den += __shfl_xor(den, off, 64);
        if (t < 32) probs_mat[(size_t)token * 32 + t] = ex / den;
        // top-4 via wave max + ballot (lowest index on ties, like lax.top_k)
        float v = l;
        float vals[TOPK]; int idxs[TOPK];
        for (int r = 0; r < TOPK; ++r) {
            float mv = v;
            for (int off = 32; off >= 1; off >>= 1) mv = fmaxf(mv, __shfl_xor(mv, off, 64));
            unsigned long long mask = __ballot(v == mv);
            int idx = __ffsll((unsigned long long)(mask & 0xffffffffull)) - 1;
            vals[r] = mv; idxs[r] = idx;
            if (t == idx) v = -3e38f;
        }
        if (t == 0) {
            float w[TOPK]; float ss = 0.f;
            for (int r = 0; r < TOPK; ++r) { w[r] = expf(vals[r] - vals[0]); ss += w[r]; }
            for (int r = 0; r < TOPK; ++r) {
                top_idx[token * TOPK + r] = idxs[r];
                top_w[token * TOPK + r] = w[r] / ss;
            }
        }
    }
}

// ---------------- aux loss + counts + offsets (1 block) ----------------
__global__ void aux_kernel(const float* __restrict__ probs_mat, const int* __restrict__ top_idx,
                           const float* __restrict__ load_ema, int* __restrict__ offsets,
                           int* __restrict__ cursors, float* __restrict__ out_aux) {
    __shared__ int cnt_s[32];
    __shared__ float ps[32];
    __shared__ float psum_part[8][32];
    int t = threadIdx.x;
    if (t < 32) cnt_s[t] = 0;
    __syncthreads();
    for (int i = t; i < N_TOK * TOPK; i += 256) atomicAdd(&cnt_s[top_idx[i]], 1);
    int e = t & 31, p = t >> 5;
    float s = 0.f;
    for (int tok = p; tok < N_TOK; tok += 8) s += probs_mat[(size_t)tok * 32 + e];
    psum_part[p][e] = s;
    __syncthreads();
    if (t < 32) {
        float tot = 0.f;
        for (int q = 0; q < 8; ++q) tot += psum_part[q][t];
        ps[t] = tot;
    }
    __syncthreads();
    if (t == 0) {
        int off = 0;
        for (int i = 0; i < 32; ++i) { offsets[i] = off; cursors[i] = off; off += cnt_s[i]; }
        offsets[32] = off;
        float base = 0.f;
        for (int i = 0; i < 32; ++i) {
            float frac = (float)cnt_s[i] / (float)(N_TOK * TOPK);
            base += frac * (ps[i] / (float)N_TOK);
        }
        base *= (float)NE;
        float sum_ema = 0.f;
        for (int i = 0; i < 32; ++i) sum_ema += load_ema[i];
        float H = 0.f;
        for (int i = 0; i < 32; ++i) {
            float lp = load_ema[i] / (sum_ema + 1e-8f);
            H -= lp * logf(lp + 1e-8f);
        }
        *out_aux = base + 0.001f * (logf((float)NE) - H);
    }
}

// ---------------- scatter token-expert pairs (+ per-pair combine weight) ----------------
__global__ void scatter_kernel(const int* __restrict__ top_idx, const float* __restrict__ top_w,
                               int* __restrict__ cursors,
                               int* __restrict__ pair_token, float* __restrict__ pair_w) {
    int token = blockIdx.x * 256 + threadIdx.x;
    if (token >= N_TOK) return;
    for (int s = 0; s < TOPK; ++s) {
        int e = top_idx[token * TOPK + s];
        int pos = atomicAdd(&cursors[e], 1);
        pair_token[pos] = token;
        pair_w[pos] = top_w[token * TOPK + s];
    }
}

// ---------------- GEMM1: h = bf16(GELU(gather(xb) @ bf16(W1[e]) + b1[e])) ----------------
// 2-phase pipelined: issue tile t+1 loads (B regs first, then g2lds A) before MFMA of tile t.
__global__ __launch_bounds__(256, 4) void gemm1_kernel(
        const __hip_bfloat16* __restrict__ xb, const float* __restrict__ w1,
        const float* __restrict__ b1, const int* __restrict__ offsets,
        const int* __restrict__ pair_token, __hip_bfloat16* __restrict__ h) {
    int e = blockIdx.z;
    int m0 = offsets[e], Me = offsets[e + 1] - m0;
    if (Me <= 0) return;
    int f0 = blockIdx.x * TN;

    __shared__ __attribute__((aligned(16))) short As[2][4 * TM * 8];   // 2 x 12 KB
    __shared__ __attribute__((aligned(16))) __hip_bfloat16 Bs[2][TN * BS_STRIDE]; // 2 x 5 KB
    __shared__ int toks[TM];

    int t = threadIdx.x;
    int w = t >> 6, ln = t & 63;
    int q = ln >> 4, lj = ln & 15;
    int bn = ln, bkb = w * 8;

    float bias[4];
#pragma unroll
    for (int ns = 0; ns < 4; ++ns) bias[ns] = b1[(size_t)e * FFN + f0 + ns * 16 + lj];

    const float* bbase = w1 + ((size_t)e * DIM + bkb) * FFN + f0 + bn;

    for (int mb = 0; mb < Me; mb += TM) {
        int mlim = Me - mb; if (mlim > TM) mlim = TM;
        __syncthreads();
        if (t < TM) {
            int r = t < mlim ? t : mlim - 1;
            toks[t] = pair_token[m0 + mb + r];
        }
        __syncthreads();

        float br[8];
        // -------- prologue: stage tile 0 into buffer 0 --------
#pragma unroll
        for (int j = 0; j < 8; ++j) br[j] = bbase[(size_t)j * FFN];
#pragma unroll
        for (int c = 0; c < 3; ++c)
            g2lds16(xb + (size_t)toks[c * 64 + ln] * DIM + w * 8,
                    &As[0][(w * TM + c * 64) * 8]);
        {
            union { __hip_bfloat16 hb[8]; int4 v; } u;
#pragma unroll
            for (int j = 0; j < 8; ++j) u.hb[j] = __float2bfloat16(br[j]);
            *(int4*)&Bs[0][bn * BS_STRIDE + bkb] = u.v;
        }
        __syncthreads();

        f32x4 acc[3][4] = {};
        int cur = 0;
        for (int k0 = 0; k0 < DIM; k0 += BK) {
            int nxt = cur ^ 1;
            bool hasNext = (k0 + BK < DIM);
            if (hasNext) {
                // B loads first (usable at vmcnt(3)), g2lds after (drained at barrier)
#pragma unroll
                for (int j = 0; j < 8; ++j) br[j] = bbase[(size_t)(k0 + BK + j) * FFN];
#pragma unroll
                for (int c = 0; c < 3; ++c)
                    g2lds16(xb + (size_t)toks[c * 64 + ln] * DIM + k0 + BK + w * 8,
                            &As[nxt][(w * TM + c * 64) * 8]);
            }
            bf16x8 af[3], bfr[4];
#pragma unroll
            for (int ms = 0; ms < 3; ++ms)
                af[ms] = *(const bf16x8*)&As[cur][(q * TM + w * 48 + ms * 16 + lj) * 8];
#pragma unroll
            for (int ns = 0; ns < 4; ++ns)
                bfr[ns] = *(const bf16x8*)&Bs[cur][(ns * 16 + lj) * BS_STRIDE + q * 8];
#pragma unroll
            for (int ms = 0; ms < 3; ++ms)
#pragma unroll
                for (int ns = 0; ns < 4; ++ns)
                    acc[ms][ns] = __builtin_amdgcn_mfma_f32_16x16x32_bf16(af[ms], bfr[ns], acc[ms][ns], 0, 0, 0);
            if (hasNext) {
                union { __hip_bfloat16 hb[8]; int4 v; } u;
#pragma unroll
                for (int j = 0; j < 8; ++j) u.hb[j] = __float2bfloat16(br[j]);
                *(int4*)&Bs[nxt][bn * BS_STRIDE + bkb] = u.v;
            }
            __syncthreads();
            cur = nxt;
        }
#pragma unroll
        for (int ms = 0; ms < 3; ++ms) {
#pragma unroll
            for (int rr = 0; rr < 4; ++rr) {
                int rit = w * 48 + ms * 16 + q * 4 + rr;
                if (rit >= mlim) continue;
                size_t rowG = (size_t)(m0 + mb + rit);
#pragma unroll
                for (int ns = 0; ns < 4; ++ns) {
                    float v = acc[ms][ns][rr] + bias[ns];
                    float g = 0.5f * v * (1.f + erff(v * 0.70710678118654752f));
                    h[rowG * FFN + f0 + ns * 16 + lj] = __float2bfloat16(g);
                }
            }
        }
    }
}

// ---------------- GEMM2 (split-K x2, fused combine): out += w_pair * (h @ bf16(W2) + b2) ----------------
__global__ __launch_bounds__(256, 4) void gemm2_kernel(
        const __hip_bfloat16* __restrict__ h, const float* __restrict__ w2,
        const float* __restrict__ b2, const int* __restrict__ offsets,
        const int* __restrict__ pair_token, const float* __restrict__ pair_w,
        float* __restrict__ out) {
    int e = blockIdx.z;
    int m0 = offsets[e], Me = offsets[e + 1] - m0;
    if (Me <= 0) return;
    int d0 = blockIdx.x * TN;
    int kbase = blockIdx.y * (FFN / 2);

    __shared__ __attribute__((aligned(16))) short As[2][4 * TM * 8];
    __shared__ __attribute__((aligned(16))) __hip_bfloat16 Bs[2][TN * BS_STRIDE];

    int t = threadIdx.x;
    int w = t >> 6, ln = t & 63;
    int q = ln >> 4, lj = ln & 15;
    int bn = ln, bkb = w * 8;

    float bias[4];
#pragma unroll
    for (int ns = 0; ns < 4; ++ns)
        bias[ns] = (blockIdx.y == 0) ? b2[(size_t)e * DIM + d0 + ns * 16 + lj] : 0.f;

    const float* bbase = w2 + ((size_t)e * FFN + kbase + bkb) * DIM + d0 + bn;

    for (int mb = 0; mb < Me; mb += TM) {
        int mlim = Me - mb; if (mlim > TM) mlim = TM;
        __syncthreads();

        float br[8];
        // -------- prologue: stage tile 0 --------
#pragma unroll
        for (int j = 0; j < 8; ++j) br[j] = bbase[(size_t)j * DIM];
#pragma unroll
        for (int c = 0; c < 3; ++c) {
            int rit = c * 64 + ln;
            int r = rit < mlim ? rit : mlim - 1;
            g2lds16(h + (size_t)(m0 + mb + r) * FFN + kbase + w * 8,
                    &As[0][(w * TM + c * 64) * 8]);
        }
        {
            union { __hip_bfloat16 hb[8]; int4 v; } u;
#pragma unroll
            for (int j = 0; j < 8; ++j) u.hb[j] = __float2bfloat16(br[j]);
            *(int4*)&Bs[0][bn * BS_STRIDE + bkb] = u.v;
        }
        __syncthreads();

        f32x4 acc[3][4] = {};
        int cur = 0;
        for (int k0 = 0; k0 < FFN / 2; k0 += BK) {
            int nxt = cur ^ 1;
            bool hasNext = (k0 + BK < FFN / 2);
            if (hasNext) {
#pragma unroll
                for (int j = 0; j < 8; ++j) br[j] = bbase[(size_t)(k0 + BK + j) * DIM];
#pragma unroll
                for (int c = 0; c < 3; ++c) {
                    int rit = c * 64 + ln;
                    int r = rit < mlim ? rit : mlim - 1;
                    g2lds16(h + (size_t)(m0 + mb + r) * FFN + kbase + k0 + BK + w * 8,
                            &As[nxt][(w * TM + c * 64) * 8]);
                }
            }
            bf16x8 af[3], bfr[4];
#pragma unroll
            for (int ms = 0; ms < 3; ++ms)
                af[ms] = *(const bf16x8*)&As[cur][(q * TM + w * 48 + ms * 16 + lj) * 8];
#pragma unroll
            for (int ns = 0; ns < 4; ++ns)
                bfr[ns] = *(const bf16x8*)&Bs[cur][(ns * 16 + lj) * BS_STRIDE + q * 8];
#pragma unroll
            for (int ms = 0; ms < 3; ++ms)
#pragma unroll
                for (int ns = 0; ns < 4; ++ns)
                    acc[ms][ns] = __builtin_amdgcn_mfma_f32_16x16x32_bf16(af[ms], bfr[ns], acc[ms][ns], 0, 0, 0);
            if (hasNext) {
                union { __hip_bfloat16 hb[8]; int4 v; } u;
#pragma unroll
                for (int j = 0; j < 8; ++j) u.hb[j] = __float2bfloat16(br[j]);
                *(int4*)&Bs[nxt][bn * BS_STRIDE + bkb] = u.v;
            }
            __syncthreads();
            cur = nxt;
        }
        // epilogue: weighted atomic scatter into out (split-K halves add independently)
#pragma unroll
        for (int ms = 0; ms < 3; ++ms) {
#pragma unroll
            for (int rr = 0; rr < 4; ++rr) {
                int rit = w * 48 + ms * 16 + q * 4 + rr;
                if (rit >= mlim) continue;
                int pr = m0 + mb + rit;
                int tok = pair_token[pr];
                float wgt = pair_w[pr];
#pragma unroll
                for (int ns = 0; ns < 4; ++ns)
                    atomicAdd(&out[(size_t)tok * DIM + d0 + ns * 16 + lj],
                              wgt * (acc[ms][ns][rr] + bias[ns]));
            }
        }
    }
}

extern "C" void kernel_launch(void* const* d_in, const int* in_sizes, int n_in,
                              void* d_out, int out_size, void* d_ws, size_t ws_size,
                              hipStream_t stream) {
    const float* x        = (const float*)d_in[0];
    const float* gate_w   = (const float*)d_in[1];
    const float* gate_b   = (const float*)d_in[2];
    const float* w1       = (const float*)d_in[3];
    const float* b1       = (const float*)d_in[4];
    const float* w2       = (const float*)d_in[5];
    const float* b2       = (const float*)d_in[6];
    const float* load_ema = (const float*)d_in[7];
    float* out = (float*)d_out;

    char* base = (char*)d_ws;
    size_t off = 0;
    auto alloc = [&](size_t bytes) {
        void* p = base + off;
        off = (off + bytes + 255) & ~(size_t)255;
        return p;
    };
    float* probs_mat = (float*)alloc(N_TOK * 32 * sizeof(float));
    int*   top_idx   = (int*)  alloc(N_TOK * TOPK * sizeof(int));
    float* top_w     = (float*)alloc(N_TOK * TOPK * sizeof(float));
    int*   offsets   = (int*)  alloc(33 * sizeof(int));
    int*   cursors   = (int*)  alloc(32 * sizeof(int));
    int*   pair_token= (int*)  alloc(N_TOK * TOPK * sizeof(int));
    float* pair_w    = (float*)alloc(N_TOK * TOPK * sizeof(float));
    __hip_bfloat16* xb = (__hip_bfloat16*)alloc((size_t)N_TOK * DIM * sizeof(__hip_bfloat16));
    __hip_bfloat16* h  = (__hip_bfloat16*)alloc((size_t)N_TOK * TOPK * FFN * sizeof(__hip_bfloat16));

    // zero the combine target first (independent of everything else)
    zero_kernel<<<N_TOK * DIM / (256 * 4), 256, 0, stream>>>((float4*)out);
    router_kernel<<<N_TOK, 256, 0, stream>>>(x, gate_w, gate_b, probs_mat, top_idx, top_w, xb);
    aux_kernel<<<1, 256, 0, stream>>>(probs_mat, top_idx, load_ema, offsets, cursors,
                                      out + (size_t)N_TOK * DIM);
    scatter_kernel<<<(N_TOK + 255) / 256, 256, 0, stream>>>(top_idx, top_w, cursors,
                                                            pair_token, pair_w);
    {
        dim3 grid(FFN / TN, 1, NE);
        gemm1_kernel<<<grid, 256, 0, stream>>>(xb, w1, b1, offsets, pair_token, h);
    }
    {
        dim3 grid(DIM / TN, 2, NE);
        gemm2_kernel<<<grid, 256, 0, stream>>>(h, w2, b2, offsets, pair_token, pair_w, out);
    }
}